// Round 7
// baseline (435.436 us; speedup 1.0000x reference)
//
#include <hip/hip_runtime.h>

#define NROWS 800000
#define SEGROWS 100000
#define K1_BLOCKS 800
#define K1_ROWS 1000
// ws float layout:
//   [0..32768)       M2 per-segment partials: 8 x 4096 (atomic, fan-in 100)
//   [32768..33280)   segment sums (atomic, fan-in 100)
//   [33280..33792)   tb fp32 (written by k2b)
//   [33792..35840)   wpb: W' as bf16 ushort[64*64], row-major [c][k] (k2b)

typedef __attribute__((ext_vector_type(8))) short bf16x8;
typedef __attribute__((ext_vector_type(4))) float f32x4;

__device__ inline unsigned short f2bf(float f) { // RNE fp32 -> bf16
    unsigned u = __builtin_bit_cast(unsigned, f);
    return (unsigned short)((u + 0x7FFFu + ((u >> 16) & 1u)) >> 16);
}

// ---------------- K0: zero the atomic accumulators ----------------
__global__ void kzero(float* __restrict__ p) {
    int t = blockIdx.x * 256 + threadIdx.x;
    if (t < 33280) p[t] = 0.f;
}

// ---------------- K1: M2 = X^T X (bf16 MFMA) + segment sums ----------------
// Barrier-free main loop (R6 version, frozen): fragment loaded directly from
// global; each wave owns independent 32-row chunks; column sums in registers.
__global__ __launch_bounds__(256, 3)
void k1_stats(const float* __restrict__ x, float* __restrict__ m2p, float* __restrict__ ssumg)
{
    __shared__ __align__(16) float smem[4096];   // 16 KB: M2 cross-wave reduce
    __shared__ float red[4][256];                // 4 KB: column-sum reduce
    int t = threadIdx.x, w = t >> 6, lane = t & 63;
    const int lg = lane >> 4, li = lane & 15;
    size_t r0 = (size_t)blockIdx.x * K1_ROWS;
    int seg = (int)(r0 / SEGROWS);               // blocks are segment-aligned (1000 | 100000)

    f32x4 acc[4][4];
#pragma unroll
    for (int p = 0; p < 4; ++p)
#pragma unroll
        for (int q = 0; q < 4; ++q) acc[p][q] = (f32x4){0.f, 0.f, 0.f, 0.f};
    float s[4] = {0.f, 0.f, 0.f, 0.f};

    for (int ch = w; ch < 32; ch += 4) {
        const int rb = 32 * ch + 8 * lg;
        const float* xp = x + (r0 + rb) * 64 + li;
        float xv[4][8];
        if (ch < 31) {
#pragma unroll
            for (int c0 = 0; c0 < 4; ++c0)
#pragma unroll
                for (int j = 0; j < 8; ++j)
                    xv[c0][j] = xp[(size_t)j * 64 + 16 * c0];
        } else {
#pragma unroll
            for (int c0 = 0; c0 < 4; ++c0)
#pragma unroll
                for (int j = 0; j < 8; ++j)
                    xv[c0][j] = (rb + j < K1_ROWS) ? xp[(size_t)j * 64 + 16 * c0] : 0.f;
        }
        bf16x8 f[4];
#pragma unroll
        for (int c0 = 0; c0 < 4; ++c0)
#pragma unroll
            for (int j = 0; j < 8; ++j) {
                s[c0] += xv[c0][j];
                f[c0][j] = (short)f2bf(xv[c0][j]);
            }
#pragma unroll
        for (int p = 0; p < 4; ++p)
#pragma unroll
            for (int q = 0; q < 4; ++q)
                acc[p][q] = __builtin_amdgcn_mfma_f32_16x16x32_bf16(f[p], f[q], acc[p][q], 0, 0, 0);
    }

    // ---- epilogue: column-sum reduce + M2 cross-wave reduce + atomic flush ----
#pragma unroll
    for (int c0 = 0; c0 < 4; ++c0) red[c0][t] = s[c0];
    int qd = lane >> 4, cl = lane & 15;
    if (w == 0) {
#pragma unroll
        for (int p = 0; p < 4; ++p)
#pragma unroll
            for (int q = 0; q < 4; ++q)
#pragma unroll
                for (int i = 0; i < 4; ++i)
                    smem[(16 * p + 4 * qd + i) * 64 + 16 * q + cl] = acc[p][q][i];
    }
    __syncthreads();
    if (t < 64) {
        int c0 = t >> 4, cc = t & 15;
        float tot = 0;
#pragma unroll
        for (int u = 0; u < 16; ++u)
            tot += red[c0][(u >> 2) * 64 + (u & 3) * 16 + cc];
        atomicAdd(&ssumg[seg * 64 + t], tot);
    }
    for (int ww = 1; ww < 4; ++ww) {
        if (w == ww) {
#pragma unroll
            for (int p = 0; p < 4; ++p)
#pragma unroll
                for (int q = 0; q < 4; ++q)
#pragma unroll
                    for (int i = 0; i < 4; ++i)
                        smem[(16 * p + 4 * qd + i) * 64 + 16 * q + cl] += acc[p][q][i];
        }
        __syncthreads();
    }
    float* m2seg = m2p + seg * 4096;
#pragma unroll
    for (int ii = 0; ii < 16; ++ii) {
        int f2 = t + 256 * ((ii + blockIdx.x) & 15);
        atomicAdd(&m2seg[f2], smem[f2]);
    }
}

// ---------------- K2b: tiny algebra -> wpb (bf16), tb (R3 version, frozen) ----------------
__global__ __launch_bounds__(256)
void k2b_solve(const int* __restrict__ o,
               const float* __restrict__ w2, const float* __restrict__ b2,
               const float* __restrict__ w1, const float* __restrict__ b1,
               const float* __restrict__ gamma, const float* __restrict__ beta,
               const float* __restrict__ m2p, const float* __restrict__ ssum,
               unsigned short* __restrict__ wpb, float* __restrict__ tbout)
{
    __shared__ __align__(16) float w1s[8192];
    __shared__ __align__(16) float w2s[4096];
    __shared__ __align__(16) float m2s[4096];
    __shared__ __align__(16) float ssums[512];
    __shared__ float means[512], hb[512], cv[512], q1p[256];
    __shared__ float Sx[64], muS[64], sS[64], cnts[8];

    int t = threadIdx.x;
    for (int i = t; i < 2048; i += 256) ((float4*)w1s)[i] = ((const float4*)w1)[i];
    for (int i = t; i < 1024; i += 256) ((float4*)w2s)[i] = ((const float4*)w2)[i];
    for (int i = t; i < 1024; i += 256) {
        float4 a = ((const float4*)m2p)[i];
#pragma unroll
        for (int s = 1; s < 8; ++s) {
            float4 b = ((const float4*)m2p)[s * 1024 + i];
            a.x += b.x; a.y += b.y; a.z += b.z; a.w += b.w;
        }
        ((float4*)m2s)[i] = a;
    }
    for (int i = t; i < 128;  i += 256) ((float4*)ssums)[i] = ((const float4*)ssum)[i];
    if (t < 8) cnts[t] = (float)(o[t] - (t ? o[t - 1] : 0));
    __syncthreads();

    for (int i = t; i < 512; i += 256) means[i] = ssums[i] / cnts[i >> 6];
    __syncthreads();
    int c = t & 63, g = t >> 6;
    for (int b = g; b < 8; b += 4) {
        float a = b2[c];
        for (int k = 0; k < 64; ++k) a = fmaf(means[b * 64 + k], w2s[c * 64 + k], a);
        hb[b * 64 + c] = fmaxf(a, 0.f);
    }
    __syncthreads();
    for (int b = g; b < 8; b += 4) {
        float a = b1[c];
        for (int k = 0; k < 64; ++k) a = fmaf(hb[b * 64 + k], w1s[c * 128 + 64 + k], a);
        cv[b * 64 + c] = a;
    }
    __syncthreads();
    if (t < 64) {
        float s = 0;
        for (int b = 0; b < 8; ++b) s += ssums[b * 64 + t];
        Sx[t] = s;
    }
    __syncthreads();
    {
        float p = 0;
        for (int j = g * 16; j < g * 16 + 16; ++j) {
            float vj = 0;
            for (int k = 0; k < 64; ++k) vj = fmaf(w1s[c * 128 + k], m2s[j * 64 + k], vj);
            p = fmaf(w1s[c * 128 + j], vj, p);
        }
        q1p[g * 64 + c] = p;
    }
    __syncthreads();
    if (t < 64) {
        const float Nf = (float)NROWS;
        float mu = 0;
        for (int k = 0; k < 64; ++k) mu = fmaf(w1s[t * 128 + k], Sx[k], mu);
        float q2 = 0, q3 = 0, msum = 0;
        for (int b = 0; b < 8; ++b) {
            float gv = cv[b * 64 + t];
            msum += cnts[b] * gv;
            q3 = fmaf(cnts[b] * gv, gv, q3);
            float dot = 0;
            for (int k = 0; k < 64; ++k) dot = fmaf(w1s[t * 128 + k], ssums[b * 64 + k], dot);
            q2 = fmaf(2.f * gv, dot, q2);
        }
        mu = (mu + msum) / Nf;
        float q1 = q1p[t] + q1p[64 + t] + q1p[128 + t] + q1p[192 + t];
        float var = (q1 + q2 + q3) / Nf - mu * mu;
        float s = gamma[t] * rsqrtf(var + 1e-5f);
        muS[t] = mu; sS[t] = s;
    }
    __syncthreads();
    for (int f = t; f < 4096; f += 256)
        wpb[f] = f2bf(w1s[(f >> 6) * 128 + (f & 63)] * sS[f >> 6]);
    for (int f = t; f < 512; f += 256)
        tbout[f] = (cv[f] - muS[f & 63]) * sS[f & 63] + beta[f & 63];
}

// ---------------- K3: out = relu(x @ W'^T + tb[seg]) via bf16 MFMA ----------------
// 3 blocks/CU (12 waves/CU) for latency hiding; no LDS, no barrier: W' frags
// and tb read directly from global (8 KB, L2/L3-hot broadcast). A-loads in two
// 8-load groups so VGPR peak stays under the 170 limit for 3 blocks/CU; group-2
// latency hides under group-1's convert+MFMA.
__global__ __launch_bounds__(256, 3)
void k3_gemm(const float* __restrict__ x, const unsigned short* __restrict__ wpb,
             const float* __restrict__ tb, float* __restrict__ out)
{
    int t = threadIdx.x, lane = t & 63, w = t >> 6;
    int cl = lane & 15, qd = lane >> 4;
    int rbase = (int)blockIdx.x * 256 + 64 * w;

    // B-frags (W'[c][k], row-major 64x64 ushort): 16 B contiguous per lane
    bf16x8 B[4][2];
#pragma unroll
    for (int n = 0; n < 4; ++n)
#pragma unroll
        for (int k0 = 0; k0 < 2; ++k0)
            B[n][k0] = *(const bf16x8*)&wpb[(16 * n + cl) * 64 + 32 * k0 + 8 * qd];

    // per-seg bias (L2-hot scalar loads, issued early)
    int seg0 = rbase / SEGROWS;
    int bnd = (seg0 + 1) * SEGROWS;
    int seg1 = min(seg0 + 1, 7);
    float tA[4], tB[4];
#pragma unroll
    for (int n = 0; n < 4; ++n) {
        tA[n] = tb[seg0 * 64 + 16 * n + cl];
        tB[n] = tb[seg1 * 64 + 16 * n + cl];
    }

    f32x4 acc[4][4];
#pragma unroll
    for (int m = 0; m < 4; ++m)
#pragma unroll
        for (int n = 0; n < 4; ++n) acc[m][n] = (f32x4){0.f, 0.f, 0.f, 0.f};

    // ---- group 1: loads for m=0,1 ----
    float4 u[2][4];
#pragma unroll
    for (int m = 0; m < 2; ++m) {
        const float* rp = x + (size_t)(rbase + 16 * m + cl) * 64 + 8 * qd;
        u[m][0] = *(const float4*)(rp);
        u[m][1] = *(const float4*)(rp + 4);
        u[m][2] = *(const float4*)(rp + 32);
        u[m][3] = *(const float4*)(rp + 36);
    }
    // convert group 1 (frees u for group 2)
    bf16x8 A[2][2];
#pragma unroll
    for (int m = 0; m < 2; ++m) {
#pragma unroll
        for (int e = 0; e < 4; ++e) {
            A[m][0][e]     = (short)f2bf(((const float*)&u[m][0])[e]);
            A[m][0][4 + e] = (short)f2bf(((const float*)&u[m][1])[e]);
            A[m][1][e]     = (short)f2bf(((const float*)&u[m][2])[e]);
            A[m][1][4 + e] = (short)f2bf(((const float*)&u[m][3])[e]);
        }
    }
    // ---- group 2: loads for m=2,3 (latency hides under MFMA below) ----
#pragma unroll
    for (int m = 0; m < 2; ++m) {
        const float* rp = x + (size_t)(rbase + 16 * (m + 2) + cl) * 64 + 8 * qd;
        u[m][0] = *(const float4*)(rp);
        u[m][1] = *(const float4*)(rp + 4);
        u[m][2] = *(const float4*)(rp + 32);
        u[m][3] = *(const float4*)(rp + 36);
    }
    // MFMA group 1
#pragma unroll
    for (int m = 0; m < 2; ++m)
#pragma unroll
        for (int n = 0; n < 4; ++n) {
            acc[m][n] = __builtin_amdgcn_mfma_f32_16x16x32_bf16(A[m][0], B[n][0], acc[m][n], 0, 0, 0);
            acc[m][n] = __builtin_amdgcn_mfma_f32_16x16x32_bf16(A[m][1], B[n][1], acc[m][n], 0, 0, 0);
        }
    // convert + MFMA group 2
#pragma unroll
    for (int m = 0; m < 2; ++m) {
#pragma unroll
        for (int e = 0; e < 4; ++e) {
            A[m][0][e]     = (short)f2bf(((const float*)&u[m][0])[e]);
            A[m][0][4 + e] = (short)f2bf(((const float*)&u[m][1])[e]);
            A[m][1][e]     = (short)f2bf(((const float*)&u[m][2])[e]);
            A[m][1][4 + e] = (short)f2bf(((const float*)&u[m][3])[e]);
        }
#pragma unroll
        for (int n = 0; n < 4; ++n) {
            acc[m + 2][n] = __builtin_amdgcn_mfma_f32_16x16x32_bf16(A[m][0], B[n][0], acc[m + 2][n], 0, 0, 0);
            acc[m + 2][n] = __builtin_amdgcn_mfma_f32_16x16x32_bf16(A[m][1], B[n][1], acc[m + 2][n], 0, 0, 0);
        }
    }

    // epilogue: +tb[seg], relu, direct stores (16 lanes = 64 B runs)
#pragma unroll
    for (int m = 0; m < 4; ++m)
#pragma unroll
        for (int i = 0; i < 4; ++i) {
            int grow = rbase + 16 * m + 4 * qd + i;
            bool hi = grow >= bnd;
#pragma unroll
            for (int n = 0; n < 4; ++n) {
                float tv = hi ? tB[n] : tA[n];
                float vv = fmaxf(acc[m][n][i] + tv, 0.f);
                out[(size_t)grow * 64 + 16 * n + cl] = vv;
            }
        }
}

extern "C" void kernel_launch(void* const* d_in, const int* in_sizes, int n_in,
                              void* d_out, int out_size, void* d_ws, size_t ws_size,
                              hipStream_t stream)
{
    const float* x  = (const float*)d_in[0];
    const int*   o  = (const int*)d_in[1];
    const float* w2 = (const float*)d_in[2];
    const float* b2 = (const float*)d_in[3];
    const float* w1 = (const float*)d_in[4];
    const float* b1 = (const float*)d_in[5];
    const float* gm = (const float*)d_in[6];
    const float* bt = (const float*)d_in[7];
    float* out = (float*)d_out;
    float* ws  = (float*)d_ws;

    float*          m2p  = ws;                    // 8 x 4096 partials
    float*          ssum = ws + 32768;
    float*          tbv  = ws + 33280;
    unsigned short* wpb  = (unsigned short*)(ws + 33792);

    kzero<<<130, 256, 0, stream>>>(ws);
    k1_stats<<<K1_BLOCKS, 256, 0, stream>>>(x, m2p, ssum);
    k2b_solve<<<1, 256, 0, stream>>>(o, w2, b2, w1, b1, gm, bt, m2p, ssum, wpb, tbv);
    k3_gemm<<<3125, 256, 0, stream>>>(x, wpb, tbv, out);
}